// Round 1
// baseline (2949.260 us; speedup 1.0000x reference)
//
#include <hip/hip_runtime.h>

typedef float v4f __attribute__((ext_vector_type(4)));

#define T_STEPS 8
#define N_NODES 100000
#define DIM     128
#define B_SEED  20000
#define S1_F    5
#define S2_F    2
#define H0_F    256
#define H1_F    128
#define C_OUT   64
#define ROWS0   120000   // B*(1+S1)

__device__ __forceinline__ v4f ld4(const float* p) { return *reinterpret_cast<const v4f*>(p); }
__device__ __forceinline__ void st4(float* p, v4f v) { *reinterpret_cast<v4f*>(p) = v; }

// ---------------- layer 0: fused gather + [64 x 256] x [256 x 256] GEMM + LIF ----------------
// A (LDS) = [self_row (K=0..127) | neigh_mean_row (K=128..255)], W = [W_l0 ; W_r0]
__global__ __launch_bounds__(256, 2)
void l0_kernel(const float* __restrict__ xt,
               const int* __restrict__ nodes,
               const int* __restrict__ nb1,   // [B*S1] for this t
               const int* __restrict__ nb2,   // [B*S1*S2] for this t
               const float* __restrict__ Wl,
               const float* __restrict__ Wr,
               const float* __restrict__ bl,
               const float* __restrict__ br,
               float* __restrict__ v0,
               unsigned char* __restrict__ s0)
{
    __shared__ float A[64 * 256];   // 64 KiB
    const int tid  = threadIdx.x;
    const int row0 = blockIdx.x * 64;

    // ---- stage A: gather self rows and averaged neighbor rows ----
    for (int idx = tid; idx < 64 * 32; idx += 256) {
        const int r = idx >> 5;           // row within tile
        const int q = (idx & 31) << 2;    // float offset within 128-wide row
        const int i = row0 + r;           // global output row
        v4f sv, nv;
        if (i < B_SEED) {
            sv = ld4(&xt[(size_t)nodes[i] * DIM + q]);
            const int* p = &nb1[i * S1_F];
            v4f a = ld4(&xt[(size_t)p[0] * DIM + q]);
            a = a + ld4(&xt[(size_t)p[1] * DIM + q]);
            a = a + ld4(&xt[(size_t)p[2] * DIM + q]);
            a = a + ld4(&xt[(size_t)p[3] * DIM + q]);
            a = a + ld4(&xt[(size_t)p[4] * DIM + q]);
            nv = a / 5.0f;
        } else {
            const int j = i - B_SEED;
            sv = ld4(&xt[(size_t)nb1[j] * DIM + q]);
            v4f a = ld4(&xt[(size_t)nb2[j * 2 + 0] * DIM + q]);
            a = a + ld4(&xt[(size_t)nb2[j * 2 + 1] * DIM + q]);
            nv = a / 2.0f;
        }
        st4(&A[r * 256 + q], sv);
        st4(&A[r * 256 + 128 + q], nv);
    }
    __syncthreads();

    const int c0    = (tid & 63) << 2;   // output col (4-wide)
    const int rbase = (tid >> 6) << 4;   // 16 rows per thread

    v4f acc[16];
#pragma unroll
    for (int rr = 0; rr < 16; ++rr) acc[rr] = (v4f)0.0f;

#pragma unroll 1
    for (int half = 0; half < 2; ++half) {
        const float* __restrict__ W = half ? Wr : Wl;
        const int kb = half << 7;
        for (int k4 = 0; k4 < 128; k4 += 4) {
            const v4f w0 = ld4(&W[(k4 + 0) * H0_F + c0]);
            const v4f w1 = ld4(&W[(k4 + 1) * H0_F + c0]);
            const v4f w2 = ld4(&W[(k4 + 2) * H0_F + c0]);
            const v4f w3 = ld4(&W[(k4 + 3) * H0_F + c0]);
#pragma unroll
            for (int rr = 0; rr < 16; ++rr) {
                const v4f a = ld4(&A[(rbase + rr) * 256 + kb + k4]);
                acc[rr] += a.x * w0;
                acc[rr] += a.y * w1;
                acc[rr] += a.z * w2;
                acc[rr] += a.w * w3;
            }
        }
    }

    const v4f bias = ld4(&bl[c0]) + ld4(&br[c0]);

#pragma unroll
    for (int rr = 0; rr < 16; ++rr) {
        const int i = row0 + rbase + rr;
        float* vp = &v0[(size_t)i * H0_F + c0];
        v4f v = ld4(vp);
        const v4f pre = acc[rr] + bias;
        v4f vn = v + (pre - v) * 0.5f;
        uchar4 sb;
        sb.x = vn.x >= 1.0f; sb.y = vn.y >= 1.0f;
        sb.z = vn.z >= 1.0f; sb.w = vn.w >= 1.0f;
        vn.x = sb.x ? 0.0f : vn.x;
        vn.y = sb.y ? 0.0f : vn.y;
        vn.z = sb.z ? 0.0f : vn.z;
        vn.w = sb.w ? 0.0f : vn.w;
        st4(vp, vn);
        *reinterpret_cast<uchar4*>(&s0[(size_t)i * H0_F + c0]) = sb;
    }
}

// ---------------- layer 1: [32 x 512] x [512 x 128] GEMM + LIF ----------------
// A = [s0_self (0/1) | mean5(s0_hop1)], W = [W_l1 ; W_r1]
__global__ __launch_bounds__(256, 2)
void l1_kernel(const unsigned char* __restrict__ s0,
               const float* __restrict__ Wl,
               const float* __restrict__ Wr,
               const float* __restrict__ bl,
               const float* __restrict__ br,
               float* __restrict__ v1,
               unsigned char* __restrict__ feats,
               const int t)
{
    __shared__ float A[32 * 512];   // 64 KiB
    const int tid  = threadIdx.x;
    const int row0 = blockIdx.x * 32;

    for (int idx = tid; idx < 32 * 64; idx += 256) {
        const int r = idx >> 6;
        const int q = (idx & 63) << 2;   // col within 256
        const int i = row0 + r;
        uchar4 sv = *reinterpret_cast<const uchar4*>(&s0[(size_t)i * H0_F + q]);
        v4f fs; fs.x = sv.x; fs.y = sv.y; fs.z = sv.z; fs.w = sv.w;
        st4(&A[r * 512 + q], fs);
        int sm0 = 0, sm1 = 0, sm2 = 0, sm3 = 0;
        const size_t base = (size_t)(B_SEED + i * S1_F) * H0_F + q;
#pragma unroll
        for (int j = 0; j < S1_F; ++j) {
            uchar4 nv = *reinterpret_cast<const uchar4*>(&s0[base + (size_t)j * H0_F]);
            sm0 += nv.x; sm1 += nv.y; sm2 += nv.z; sm3 += nv.w;
        }
        v4f fm;
        fm.x = (float)sm0 / 5.0f; fm.y = (float)sm1 / 5.0f;
        fm.z = (float)sm2 / 5.0f; fm.w = (float)sm3 / 5.0f;
        st4(&A[r * 512 + 256 + q], fm);
    }
    __syncthreads();

    const int c0    = (tid & 31) << 2;  // 128 cols
    const int rbase = (tid >> 5) << 2;  // 4 rows per thread

    v4f acc[4];
#pragma unroll
    for (int rr = 0; rr < 4; ++rr) acc[rr] = (v4f)0.0f;

#pragma unroll 1
    for (int half = 0; half < 2; ++half) {
        const float* __restrict__ W = half ? Wr : Wl;
        const int kb = half << 8;
        for (int k4 = 0; k4 < 256; k4 += 4) {
            const v4f w0 = ld4(&W[(k4 + 0) * H1_F + c0]);
            const v4f w1 = ld4(&W[(k4 + 1) * H1_F + c0]);
            const v4f w2 = ld4(&W[(k4 + 2) * H1_F + c0]);
            const v4f w3 = ld4(&W[(k4 + 3) * H1_F + c0]);
#pragma unroll
            for (int rr = 0; rr < 4; ++rr) {
                const v4f a = ld4(&A[(rbase + rr) * 512 + kb + k4]);
                acc[rr] += a.x * w0;
                acc[rr] += a.y * w1;
                acc[rr] += a.z * w2;
                acc[rr] += a.w * w3;
            }
        }
    }

    const v4f bias = ld4(&bl[c0]) + ld4(&br[c0]);

#pragma unroll
    for (int rr = 0; rr < 4; ++rr) {
        const int i = row0 + rbase + rr;
        float* vp = &v1[(size_t)i * H1_F + c0];
        v4f v = ld4(vp);
        const v4f pre = acc[rr] + bias;
        v4f vn = v + (pre - v) * 0.5f;
        uchar4 sb;
        sb.x = vn.x >= 1.0f; sb.y = vn.y >= 1.0f;
        sb.z = vn.z >= 1.0f; sb.w = vn.w >= 1.0f;
        vn.x = sb.x ? 0.0f : vn.x;
        vn.y = sb.y ? 0.0f : vn.y;
        vn.z = sb.z ? 0.0f : vn.z;
        vn.w = sb.w ? 0.0f : vn.w;
        st4(vp, vn);
        *reinterpret_cast<uchar4*>(&feats[(size_t)i * (T_STEPS * H1_F) + t * H1_F + c0]) = sb;
    }
}

// ---------------- pool: [32 x 1024] x [1024 x 64] GEMM ----------------
__global__ __launch_bounds__(256, 2)
void pool_kernel(const unsigned char* __restrict__ feats,
                 const float* __restrict__ Wp,
                 const float* __restrict__ bp,
                 float* __restrict__ out)
{
    __shared__ unsigned char F[32 * 1024];   // 32 KiB
    const int tid  = threadIdx.x;
    const int row0 = blockIdx.x * 32;

    for (int idx = tid; idx < 32 * 256; idx += 256) {
        const int r = idx >> 8;
        const int q = (idx & 255) << 2;
        *reinterpret_cast<uchar4*>(&F[r * 1024 + q]) =
            *reinterpret_cast<const uchar4*>(&feats[(size_t)(row0 + r) * 1024 + q]);
    }
    __syncthreads();

    const int c0    = (tid & 15) << 2;  // 64 cols
    const int rbase = (tid >> 4) << 1;  // 2 rows per thread

    v4f acc[2];
    acc[0] = (v4f)0.0f; acc[1] = (v4f)0.0f;

    for (int k4 = 0; k4 < 1024; k4 += 4) {
        const v4f w0 = ld4(&Wp[(k4 + 0) * C_OUT + c0]);
        const v4f w1 = ld4(&Wp[(k4 + 1) * C_OUT + c0]);
        const v4f w2 = ld4(&Wp[(k4 + 2) * C_OUT + c0]);
        const v4f w3 = ld4(&Wp[(k4 + 3) * C_OUT + c0]);
#pragma unroll
        for (int rr = 0; rr < 2; ++rr) {
            uchar4 a = *reinterpret_cast<const uchar4*>(&F[(rbase + rr) * 1024 + k4]);
            acc[rr] += (float)a.x * w0;
            acc[rr] += (float)a.y * w1;
            acc[rr] += (float)a.z * w2;
            acc[rr] += (float)a.w * w3;
        }
    }

    const v4f bias = ld4(&bp[c0]);
#pragma unroll
    for (int rr = 0; rr < 2; ++rr) {
        const int i = row0 + rbase + rr;
        st4(&out[(size_t)i * C_OUT + c0], acc[rr] + bias);
    }
}

extern "C" void kernel_launch(void* const* d_in, const int* in_sizes, int n_in,
                              void* d_out, int out_size, void* d_ws, size_t ws_size,
                              hipStream_t stream)
{
    const float* x    = (const float*)d_in[0];
    const float* Wl0  = (const float*)d_in[1];
    const float* bl0  = (const float*)d_in[2];
    const float* Wr0  = (const float*)d_in[3];
    const float* br0  = (const float*)d_in[4];
    const float* Wl1  = (const float*)d_in[5];
    const float* bl1  = (const float*)d_in[6];
    const float* Wr1  = (const float*)d_in[7];
    const float* br1  = (const float*)d_in[8];
    const float* Wp   = (const float*)d_in[9];
    const float* bp   = (const float*)d_in[10];
    const int* nodes  = (const int*)d_in[11];
    const int* nbr1   = (const int*)d_in[12];
    const int* nbr2   = (const int*)d_in[13];
    float* out = (float*)d_out;

    // workspace layout (bytes):
    //   v0   : 120000*256*4 = 122,880,000
    //   v1   :  20000*128*4 =  10,240,000
    //   s0   : 120000*256   =  30,720,000
    //   feats:  20000*1024  =  20,480,000
    char* ws = (char*)d_ws;
    float* v0 = (float*)ws;
    float* v1 = (float*)(ws + 122880000);
    unsigned char* s0    = (unsigned char*)(ws + 133120000);
    unsigned char* feats = (unsigned char*)(ws + 163840000);

    // zero the membrane state (ws is poisoned 0xAA before every launch)
    hipMemsetAsync(v0, 0, 133120000, stream);

    for (int t = 0; t < T_STEPS; ++t) {
        const float* xt = x + (size_t)t * N_NODES * DIM;
        const int* nb1  = nbr1 + (size_t)t * B_SEED * S1_F;
        const int* nb2  = nbr2 + (size_t)t * B_SEED * S1_F * S2_F;
        l0_kernel<<<ROWS0 / 64, 256, 0, stream>>>(xt, nodes, nb1, nb2,
                                                  Wl0, Wr0, bl0, br0, v0, s0);
        l1_kernel<<<B_SEED / 32, 256, 0, stream>>>(s0, Wl1, Wr1, bl1, br1,
                                                   v1, feats, t);
    }
    pool_kernel<<<B_SEED / 32, 256, 0, stream>>>(feats, Wp, bp, out);
}